// Round 9
// baseline (444.301 us; speedup 1.0000x reference)
//
#include <hip/hip_runtime.h>

// Viterbi decoder forward: B=32, T=256, L=48, START=46, END=47.
// R9: barrier-free single-wave recurrences + DMA ring + deferred argmax.
//  64 WGs x 256 thr. role = bid>>5 (0:Viterbi, 1:LSE), b = bid&31.
//  Wave 0 runs the 255-step chain alone: lane j holds state[j]; the 48
//  source terms come via readlane broadcast (no barriers, no LDS merge).
//  Emissions staged by global_load_lds into a 6-row LDS ring, counted
//  s_waitcnt vmcnt(36) (never drained in-loop) -- deterministic (R4/R5).
//  Viterbi is value-only in the loop; backpointers recomputed afterwards
//  by all 4 waves with coalesced reads (bit-identical math), then the
//  proven chunked traceback. LSE in probability domain (ldexp renorm).

#define TT 256
#define LL 48
#define ROWF 2304          // 48*48 floats per time-row
#define LSTART 46
#define LEND 47
#define BB 32
#define LOG2E 1.44269504088896f
#define LN2 0.693147180559945f

#define GLL(GP, LP) __builtin_amdgcn_global_load_lds( \
    (const __attribute__((address_space(1))) void*)(GP), \
    (__attribute__((address_space(3))) void*)(LP), 16, 0, 0)

#define RL(var, lane) __int_as_float(__builtin_amdgcn_readlane(__float_as_int(var), (lane)))

// stage one emission row into ring slot SW (9 x 1KB, linear, R5 pattern)
#define STAGE_ROW(ROW, SW) do { \
    const float* gs_ = emB + (size_t)(ROW)*ROWF + 4*j; \
    float* ls_ = ring + (SW)*ROWF; \
    _Pragma("unroll") \
    for (int n = 0; n < 9; ++n) GLL(gs_ + n*256, ls_ + n*256); \
  } while (0)

// Viterbi step: stage row t+5, wait row t+1, prefetch it into NXT (off
// chain), then the chain: c[i]=CUR[i]+best[i], value-only max tree.
#define STEPV(CUR, NXT) do { \
    { int row_ = t + 5; row_ = row_ > 255 ? 255 : row_; \
      STAGE_ROW(row_, sw); sw = (sw == 5) ? 0 : sw + 1; } \
    asm volatile("s_waitcnt vmcnt(36)" ::: "memory"); \
    { const float* rp_ = ring + sr*ROWF + jl; \
      _Pragma("unroll") \
      for (int i = 0; i < LL; ++i) (NXT)[i] = rp_[i*LL] + trg[i]; \
      sr = (sr == 5) ? 0 : sr + 1; } \
    { float c[LL]; \
      _Pragma("unroll") \
      for (int i = 0; i < LL; ++i) c[i] = (CUR)[i] + RL(vbest, i); \
      _Pragma("unroll") \
      for (int i = 0; i < 24; ++i) c[i] = fmaxf(c[i], c[i+24]); \
      _Pragma("unroll") \
      for (int i = 0; i < 12; ++i) c[i] = fmaxf(c[i], c[i+12]); \
      _Pragma("unroll") \
      for (int i = 0; i < 6; ++i)  c[i] = fmaxf(c[i], c[i+6]); \
      c[0] = fmaxf(c[0], c[3]); c[1] = fmaxf(c[1], c[4]); c[2] = fmaxf(c[2], c[5]); \
      float bv_ = fmaxf(fmaxf(c[0], c[1]), c[2]); \
      bool upd_ = act && (t < len); \
      vbest = upd_ ? bv_ : vbest; \
      if (act) bestHist[t*LL + j] = vbest; } \
    ++t; \
  } while (0)

#define STEPV_FIN(CUR) do { \
    float c[LL]; \
    _Pragma("unroll") \
    for (int i = 0; i < LL; ++i) c[i] = (CUR)[i] + RL(vbest, i); \
    _Pragma("unroll") \
    for (int i = 0; i < 24; ++i) c[i] = fmaxf(c[i], c[i+24]); \
    _Pragma("unroll") \
    for (int i = 0; i < 12; ++i) c[i] = fmaxf(c[i], c[i+12]); \
    _Pragma("unroll") \
    for (int i = 0; i < 6; ++i)  c[i] = fmaxf(c[i], c[i+6]); \
    c[0] = fmaxf(c[0], c[3]); c[1] = fmaxf(c[1], c[4]); c[2] = fmaxf(c[2], c[5]); \
    float bv_ = fmaxf(fmaxf(c[0], c[1]), c[2]); \
    bool upd_ = act && (t < len); \
    vbest = upd_ ? bv_ : vbest; \
    if (act) bestHist[t*LL + j] = vbest; \
    ++t; \
  } while (0)

// LSE step, probability domain: P_t[j] = sum_i E[i,j] * P[i], E=exp2(etr2).
#define STEPL(EC, EN) do { \
    { int row_ = t + 5; row_ = row_ > 255 ? 255 : row_; \
      STAGE_ROW(row_, sw); sw = (sw == 5) ? 0 : sw + 1; } \
    asm volatile("s_waitcnt vmcnt(36)" ::: "memory"); \
    { const float* rp_ = ring + sr*ROWF + jl; \
      _Pragma("unroll") \
      for (int i = 0; i < LL; ++i) \
        (EN)[i] = exp2f(fmaf(rp_[i*LL], LOG2E, trg2[i])); \
      sr = (sr == 5) ? 0 : sr + 1; } \
    { float a0 = 0.f, a1 = 0.f, a2 = 0.f, a3 = 0.f; \
      _Pragma("unroll") \
      for (int i = 0; i < LL; i += 4) { \
        a0 = fmaf((EC)[i+0], RL(P, i+0), a0); \
        a1 = fmaf((EC)[i+1], RL(P, i+1), a1); \
        a2 = fmaf((EC)[i+2], RL(P, i+2), a2); \
        a3 = fmaf((EC)[i+3], RL(P, i+3), a3); \
      } \
      float Pn_ = (a0 + a1) + (a2 + a3); \
      int rb_ = __builtin_amdgcn_readlane(__float_as_int(Pn_), 0); \
      int e_ = ((rb_ >> 23) & 255) - 127; \
      bool upd_ = (t < len); \
      P    = upd_ ? __builtin_ldexpf(Pn_, -e_) : P; \
      macc = upd_ ? macc + (float)e_ : macc; } \
    ++t; \
  } while (0)

#define STEPL_FIN(EC) do { \
    float a0 = 0.f, a1 = 0.f, a2 = 0.f, a3 = 0.f; \
    _Pragma("unroll") \
    for (int i = 0; i < LL; i += 4) { \
      a0 = fmaf((EC)[i+0], RL(P, i+0), a0); \
      a1 = fmaf((EC)[i+1], RL(P, i+1), a1); \
      a2 = fmaf((EC)[i+2], RL(P, i+2), a2); \
      a3 = fmaf((EC)[i+3], RL(P, i+3), a3); \
    } \
    float Pn_ = (a0 + a1) + (a2 + a3); \
    int rb_ = __builtin_amdgcn_readlane(__float_as_int(Pn_), 0); \
    int e_ = ((rb_ >> 23) & 255) - 127; \
    bool upd_ = (t < len); \
    P    = upd_ ? __builtin_ldexpf(Pn_, -e_) : P; \
    macc = upd_ ? macc + (float)e_ : macc; \
    ++t; \
  } while (0)

__device__ __forceinline__ int load_len(const int* len_raw, int b) {
  // lengths int32-or-int64 detection (values 128..256)
  bool is64 = (len_raw[1] == 0) && (len_raw[3] == 0) && (len_raw[5] == 0);
  int len = is64 ? len_raw[2*b] : len_raw[b];
  if (len > TT) len = TT;
  if (len < 1) len = 1;
  return len;
}

__launch_bounds__(256, 1)
__global__ void viterbi_fwd(const float* __restrict__ em,
                            const float* __restrict__ tr,
                            const int* __restrict__ len_raw,
                            float* __restrict__ out,
                            float* __restrict__ ws)
{
  const int role = blockIdx.x >> 5;   // 0 = Viterbi, 1 = LSE
  const int b    = blockIdx.x & 31;
  const int tid  = threadIdx.x;
  const int w    = tid >> 6;
  const int j    = tid & 63;
  const bool act = (j < LL);
  const int jl   = act ? j : (LL - 1);
  const int len  = load_len(len_raw, b);

  __shared__ float ring[6*ROWF];          // 55 KiB DMA ring
  __shared__ float bestHist[TT*LL];       // 49 KiB (role 0)
  __shared__ float trL[ROWF];             // 9 KiB transition copy (role 0)
  __shared__ unsigned char bp[TT*LL];
  __shared__ unsigned char cmp_[16*LL];
  __shared__ unsigned char entry_[16];
  __shared__ unsigned char raw[TT];

  const float* emB = em + (size_t)b*TT*ROWF;

  if (role == 0) {
    // ===================== Viterbi =====================
    if (w == 0) {
      float trg[LL];
      #pragma unroll
      for (int i = 0; i < LL; ++i) trg[i] = tr[i*LL + jl];
      const float init = emB[LSTART*LL + jl] + trg[LSTART];
      float vbest = act ? init : -INFINITY;
      if (act) bestHist[j] = vbest;       // row 0 for bp recompute

      #pragma unroll
      for (int r = 1; r <= 5; ++r) STAGE_ROW(r, r);
      asm volatile("s_waitcnt vmcnt(36)" ::: "memory");   // row 1 landed

      float curA[LL], curB[LL];
      {
        const float* rp = ring + ROWF + jl;
        #pragma unroll
        for (int i = 0; i < LL; ++i) curA[i] = rp[i*LL] + trg[i];
      }
      int sr = 2, sw = 0, t = 1;
      #pragma unroll 1
      for (int it = 0; it < 127; ++it) {  // t = 1..254
        STEPV(curA, curB);
        STEPV(curB, curA);
      }
      STEPV_FIN(curA);                    // t = 255
      if (j == LEND) ws[BB + b] = vbest;  // best[END]
    } else {
      // waves 1-3: bp boundary rows + transition copy for recompute
      const int t3 = tid - 64;            // 0..191
      for (int idx = t3; idx < LL; idx += 192) bp[idx] = (unsigned char)LSTART;
      for (int idx = len*LL + t3; idx < TT*LL; idx += 192) bp[idx] = (unsigned char)LEND;
      for (int idx = t3; idx < ROWF; idx += 192) trL[idx] = tr[idx];
    }
    __syncthreads();

    // ---- backpointer recompute, 4 waves, coalesced, bit-identical ----
    {
      float trc[LL];
      #pragma unroll
      for (int i = 0; i < LL; ++i) trc[i] = trL[i*LL + jl];
      #pragma unroll 1
      for (int m = 0; m < 64; ++m) {
        const int t2 = 1 + w + 4*m;       // covers 1..256 once
        if (t2 < len) {                   // wave-uniform; t2<len<=256 -> t2<=255
          const float* srow = emB + (size_t)t2*ROWF + jl;
          float bh[LL];
          #pragma unroll
          for (int q = 0; q < 12; ++q) {  // broadcast reads, conflict-free
            const float4 v4 = *(const float4*)&bestHist[(t2-1)*LL + 4*q];
            bh[4*q] = v4.x; bh[4*q+1] = v4.y; bh[4*q+2] = v4.z; bh[4*q+3] = v4.w;
          }
          float bv = -INFINITY; int ba = 0;
          #pragma unroll
          for (int i = 0; i < LL; ++i) {  // ascending i + strict > = first occurrence
            float cc = (srow[i*LL] + trc[i]) + bh[i];
            if (cc > bv) { bv = cc; ba = i; }
          }
          if (act) bp[t2*LL + j] = (unsigned char)ba;
        }
      }
    }
    __syncthreads();

    // ---- traceback, chunked (16 chunks x 16 steps) ----
    for (int idx = tid; idx < 16*LL; idx += 256) {
      int c = idx / LL, l = idx - c*LL;
      int pc = l;
      #pragma unroll
      for (int k = 15; k >= 0; --k) pc = bp[(16*c + k)*LL + pc];
      cmp_[c*LL + l] = (unsigned char)pc;
    }
    __syncthreads();
    if (tid == 0) {
      int pc = LEND;
      for (int c = 15; c >= 0; --c) { entry_[c] = (unsigned char)pc; pc = cmp_[c*LL + pc]; }
    }
    __syncthreads();
    if (tid < 16) {
      int c = tid, pc = entry_[c];
      #pragma unroll
      for (int k = 15; k >= 0; --k) { int t2 = 16*c + k; pc = bp[t2*LL + pc]; raw[t2] = (unsigned char)pc; }
    }
    __syncthreads();
    out[(size_t)b*TT + tid] = (tid < TT - 1) ? (float)raw[tid + 1] : (float)LEND;

  } else {
    // ===================== logsumexp =====================
    if (w != 0) return;                   // no barriers anywhere in this role
    float trg2[LL];
    #pragma unroll
    for (int i = 0; i < LL; ++i) trg2[i] = tr[i*LL + jl] * LOG2E;
    const float init = emB[LSTART*LL + jl] + tr[LSTART*LL + jl];
    const float m2 = RL(init, 0) * LOG2E;
    float P = act ? exp2f(init * LOG2E - m2) : 0.f;
    float macc = m2;

    #pragma unroll
    for (int r = 1; r <= 5; ++r) STAGE_ROW(r, r);
    asm volatile("s_waitcnt vmcnt(36)" ::: "memory");

    float eA[LL], eB[LL];
    {
      const float* rp = ring + ROWF + jl;
      #pragma unroll
      for (int i = 0; i < LL; ++i) eA[i] = exp2f(fmaf(rp[i*LL], LOG2E, trg2[i]));
    }
    int sr = 2, sw = 0, t = 1;
    #pragma unroll 1
    for (int it = 0; it < 127; ++it) {    // t = 1..254
      STEPL(eA, eB);
      STEPL(eB, eA);
    }
    STEPL_FIN(eA);                        // t = 255
    if (j == LEND) ws[b] = (macc + __log2f(P)) * LN2;   // upto[END] in nats
  }
}

__global__ void viterbi_score(const float* __restrict__ ws, float* __restrict__ out)
{
  int b = threadIdx.x;
  if (b < BB) out[(size_t)BB*TT + b] = ws[BB + b] - ws[b];  // best - upto
}

extern "C" void kernel_launch(void* const* d_in, const int* in_sizes, int n_in,
                              void* d_out, int out_size, void* d_ws, size_t ws_size,
                              hipStream_t stream) {
  const float* em  = (const float*)d_in[0];
  const float* tr  = (const float*)d_in[1];
  const int*   ln  = (const int*)d_in[2];
  float* out = (float*)d_out;
  float* ws  = (float*)d_ws;
  viterbi_fwd<<<dim3(64), dim3(256), 0, stream>>>(em, tr, ln, out, ws);
  viterbi_score<<<dim3(1), dim3(64), 0, stream>>>(ws, out);
}

// Round 10
// 184.789 us; speedup vs baseline: 2.4044x; 2.4044x over previous
//
#include <hip/hip_runtime.h>

// Viterbi decoder forward: B=32, T=256, L=48, START=46, END=47.
// R10: R3's 4-wave/12-i structure + DMA ring staging + cross-barrier
// software pipelining. Per WG (4 waves, lane j = target label):
//   iter t: [read merge partials of t-1] -> under its latency: etr adds,
//   DMA issue (row t+5), vmcnt(12), LDS->reg prefetch (row t+1) ->
//   select vbest_{t-1} (+bp byte) -> 12 readlane + tree -> write partials
//   of t -> lgkm(0) + raw s_barrier (vmcnt NOT drained; DMA in flight).
// Roles: blocks 0-31 Viterbi (inline argmax + traceback), 32-63 LSE
// (probability domain P = E^T P, ldexp renorm, one log2 at the end).

#define TT 256
#define LL 48
#define ROWF 2304          // 48*48 floats per time-row
#define LSTART 46
#define LEND 47
#define BB 32
#define LOG2E 1.44269504088896f
#define LN2 0.693147180559945f

#define GLL16(GP, LP) __builtin_amdgcn_global_load_lds( \
    (const __attribute__((address_space(1))) void*)(GP), \
    (__attribute__((address_space(3))) void*)(LP), 16, 0, 0)
#define GLL4(GP, LP) __builtin_amdgcn_global_load_lds( \
    (const __attribute__((address_space(1))) void*)(GP), \
    (__attribute__((address_space(3))) void*)(LP), 4, 0, 0)

#define RL(var, lane) __int_as_float(__builtin_amdgcn_readlane(__float_as_int(var), (lane)))

#define BARRIER() do { \
    asm volatile("s_waitcnt lgkmcnt(0)" ::: "memory"); \
    __builtin_amdgcn_s_barrier(); \
  } while (0)
#define WAITVM(N) asm volatile("s_waitcnt vmcnt(" #N ")" ::: "memory")

// strict > with ordered pairing == jnp.argmax first-occurrence semantics
#define AMAX(vx, ix, vy, iy) do { if ((vy) > (vx)) { (vx)=(vy); (ix)=(iy);} } while(0)

// stage this wave's 576-float i-slice of emission row ROW into slot SLOT
// (2 x 16B-wide + 1 x 4B-wide global_load_lds; 3 vmcnt events per wave)
#define STAGE(ROW, SLOT) do { \
    const float* gs_ = emB + (size_t)(ROW)*ROWF + wslice; \
    float* ls_ = ring + (SLOT)*ROWF + wslice; \
    GLL16(gs_ + 4*j, ls_); \
    GLL16(gs_ + 256 + 4*j, ls_ + 256); \
    GLL4 (gs_ + 512 + j, ls_ + 512); \
  } while (0)

// 12-candidate partial max/argmax tree -> partV[PW][w][j]
#define PARTIALS_V(ETR, PW) do { \
    float cv[12]; int ci[12]; \
    _Pragma("unroll") \
    for (int k = 0; k < 12; ++k) { \
      cv[k] = (ETR)[k] + RL(vbest, 12*w + k); ci[k] = 12*w + k; } \
    AMAX(cv[0],ci[0],cv[1],ci[1]);  AMAX(cv[2],ci[2],cv[3],ci[3]); \
    AMAX(cv[4],ci[4],cv[5],ci[5]);  AMAX(cv[6],ci[6],cv[7],ci[7]); \
    AMAX(cv[8],ci[8],cv[9],ci[9]);  AMAX(cv[10],ci[10],cv[11],ci[11]); \
    AMAX(cv[0],ci[0],cv[2],ci[2]);  AMAX(cv[4],ci[4],cv[6],ci[6]); \
    AMAX(cv[8],ci[8],cv[10],ci[10]); \
    AMAX(cv[0],ci[0],cv[4],ci[4]); \
    AMAX(cv[0],ci[0],cv[8],ci[8]); \
    partV[PW][w][j] = make_float2(cv[0], __int_as_float(ci[0])); \
  } while (0)

#define ITER_V(T_, RAWP, RAWN) do { \
    const int pr_ = ((T_)-1) & 1; \
    float2 m0_ = partV[pr_][0][j], m1_ = partV[pr_][1][j]; \
    float2 m2_ = partV[pr_][2][j], m3_ = partV[pr_][3][j]; \
    float etr_[12]; \
    _Pragma("unroll") \
    for (int k = 0; k < 12; ++k) etr_[k] = (RAWP)[k] + trg[k]; \
    { int row_ = (T_) + 5; if (row_ > 255) row_ = 255; \
      STAGE(row_, sw); sw = (sw == 5) ? 0 : sw + 1; } \
    WAITVM(12); \
    { const float* rp_ = ring + sr*ROWF + jl; \
      _Pragma("unroll") \
      for (int k = 0; k < 12; ++k) (RAWN)[k] = rp_[(12*w+k)*LL]; \
      sr = (sr == 5) ? 0 : sr + 1; } \
    float bv_ = m0_.x; int ba_ = __float_as_int(m0_.y); \
    AMAX(bv_, ba_, m1_.x, __float_as_int(m1_.y)); \
    AMAX(bv_, ba_, m2_.x, __float_as_int(m2_.y)); \
    AMAX(bv_, ba_, m3_.x, __float_as_int(m3_.y)); \
    { const bool upd_ = act && (((T_)-1) < len); \
      vbest = upd_ ? bv_ : vbest; \
      if (w == 0 && upd_) bp[((T_)-1)*LL + j] = (unsigned char)ba_; } \
    PARTIALS_V(etr_, (T_) & 1); \
    BARRIER(); \
  } while (0)

#define PARTIALS_L(EE, PW) do { \
    float a0 = 0.f, a1 = 0.f, a2 = 0.f, a3 = 0.f; \
    _Pragma("unroll") \
    for (int k = 0; k < 12; k += 4) { \
      a0 = fmaf((EE)[k+0], RL(P, 12*w + k + 0), a0); \
      a1 = fmaf((EE)[k+1], RL(P, 12*w + k + 1), a1); \
      a2 = fmaf((EE)[k+2], RL(P, 12*w + k + 2), a2); \
      a3 = fmaf((EE)[k+3], RL(P, 12*w + k + 3), a3); \
    } \
    partS[PW][w][j] = (a0 + a1) + (a2 + a3); \
  } while (0)

#define ITER_L(T_, RAWP, RAWN) do { \
    const int pr_ = ((T_)-1) & 1; \
    float s0_ = partS[pr_][0][j], s1_ = partS[pr_][1][j]; \
    float s2_ = partS[pr_][2][j], s3_ = partS[pr_][3][j]; \
    float ee_[12]; \
    _Pragma("unroll") \
    for (int k = 0; k < 12; ++k) \
      ee_[k] = exp2f(fmaf((RAWP)[k], LOG2E, trg2[k])); \
    { int row_ = (T_) + 5; if (row_ > 255) row_ = 255; \
      STAGE(row_, sw); sw = (sw == 5) ? 0 : sw + 1; } \
    WAITVM(12); \
    { const float* rp_ = ring + sr*ROWF + jl; \
      _Pragma("unroll") \
      for (int k = 0; k < 12; ++k) (RAWN)[k] = rp_[(12*w+k)*LL]; \
      sr = (sr == 5) ? 0 : sr + 1; } \
    float Pn_ = (s0_ + s1_) + (s2_ + s3_); \
    { int rb_ = __builtin_amdgcn_readlane(__float_as_int(Pn_), 0); \
      int e_ = ((rb_ >> 23) & 255) - 127; \
      const bool upd_ = (((T_)-1) < len); \
      P    = upd_ ? __builtin_ldexpf(Pn_, -e_) : P; \
      macc = upd_ ? macc + (float)e_ : macc; } \
    PARTIALS_L(ee_, (T_) & 1); \
    BARRIER(); \
  } while (0)

__device__ __forceinline__ int load_len(const int* len_raw, int b) {
  // lengths int32-or-int64 detection (values 128..256)
  bool is64 = (len_raw[1] == 0) && (len_raw[3] == 0) && (len_raw[5] == 0);
  int len = is64 ? len_raw[2*b] : len_raw[b];
  if (len > TT) len = TT;
  if (len < 1) len = 1;
  return len;
}

__launch_bounds__(256, 1)
__global__ void viterbi_fwd(const float* __restrict__ em,
                            const float* __restrict__ tr,
                            const int* __restrict__ len_raw,
                            float* __restrict__ out,
                            float* __restrict__ ws)
{
  const int role = blockIdx.x >> 5;   // 0 = Viterbi, 1 = LSE
  const int b    = blockIdx.x & 31;
  const int tid  = threadIdx.x;
  const int w    = tid >> 6;
  const int j    = tid & 63;
  const bool act = (j < LL);
  const int jl   = act ? j : (LL - 1);
  const int wslice = w * 576;         // this wave's i-slice offset in a row
  const int len  = load_len(len_raw, b);

  __shared__ float ring[6*ROWF];          // 55 KiB DMA ring
  __shared__ float2 partV[2][4][64];
  __shared__ float  partS[2][4][64];
  __shared__ unsigned char bp[TT*LL];
  __shared__ unsigned char cmp_[16*LL];
  __shared__ unsigned char entry_[16];
  __shared__ unsigned char raw[TT];

  const float* emB = em + (size_t)b*TT*ROWF;

  if (role == 0) {
    // ===================== Viterbi =====================
    for (int idx = tid; idx < LL; idx += 256) bp[idx] = (unsigned char)LSTART;
    for (int idx = len*LL + tid; idx < TT*LL; idx += 256) bp[idx] = (unsigned char)LEND;
    __syncthreads();

    float trg[12];
    #pragma unroll
    for (int k = 0; k < 12; ++k) trg[k] = tr[(12*w + k)*LL + jl];
    const float init = emB[LSTART*LL + jl] + tr[LSTART*LL + jl];
    float vbest = act ? init : -INFINITY;

    // prologue: rows 1..6 -> slots 1..5,0
    STAGE(1,1); STAGE(2,2); STAGE(3,3); STAGE(4,4); STAGE(5,5); STAGE(6,0);
    WAITVM(15);                           // 18 issued, <=15 -> row 1 landed
    float rawA[12], rawB[12];
    {
      const float* rp = ring + 1*ROWF + jl;
      float e1[12];
      #pragma unroll
      for (int k = 0; k < 12; ++k) e1[k] = rp[(12*w+k)*LL] + trg[k];
      PARTIALS_V(e1, 1);                  // partials of t=1
    }
    WAITVM(12);                           // row 2 landed
    {
      const float* rp = ring + 2*ROWF + jl;
      #pragma unroll
      for (int k = 0; k < 12; ++k) rawA[k] = rp[(12*w+k)*LL];
    }
    BARRIER();

    int sr = 3, sw = 1;
    #pragma unroll 1
    for (int t = 2; t <= 254; t += 2) {
      ITER_V(t,     rawA, rawB);
      ITER_V(t + 1, rawB, rawA);
    }
    // final merge: step 255 partials are in partV[1]
    {
      float2 m0 = partV[1][0][j], m1 = partV[1][1][j];
      float2 m2 = partV[1][2][j], m3 = partV[1][3][j];
      float bv = m0.x; int ba = __float_as_int(m0.y);
      AMAX(bv, ba, m1.x, __float_as_int(m1.y));
      AMAX(bv, ba, m2.x, __float_as_int(m2.y));
      AMAX(bv, ba, m3.x, __float_as_int(m3.y));
      const bool upd = act && (255 < len);
      vbest = upd ? bv : vbest;
      if (w == 0 && upd) bp[255*LL + j] = (unsigned char)ba;
    }
    if (tid == LEND) ws[BB + b] = vbest;  // best[END]
    __syncthreads();

    // ---- traceback, chunked (16 chunks x 16 steps) ----
    for (int idx = tid; idx < 16*LL; idx += 256) {
      int c = idx / LL, l = idx - c*LL;
      int pc = l;
      #pragma unroll
      for (int k = 15; k >= 0; --k) pc = bp[(16*c + k)*LL + pc];
      cmp_[c*LL + l] = (unsigned char)pc;
    }
    __syncthreads();
    if (tid == 0) {
      int pc = LEND;
      for (int c = 15; c >= 0; --c) { entry_[c] = (unsigned char)pc; pc = cmp_[c*LL + pc]; }
    }
    __syncthreads();
    if (tid < 16) {
      int c = tid, pc = entry_[c];
      #pragma unroll
      for (int k = 15; k >= 0; --k) { int t2 = 16*c + k; pc = bp[t2*LL + pc]; raw[t2] = (unsigned char)pc; }
    }
    __syncthreads();
    out[(size_t)b*TT + tid] = (tid < TT - 1) ? (float)raw[tid + 1] : (float)LEND;

  } else {
    // ===================== logsumexp (probability domain) =====================
    float trg2[12];
    #pragma unroll
    for (int k = 0; k < 12; ++k) trg2[k] = tr[(12*w + k)*LL + jl] * LOG2E;
    const float init = emB[LSTART*LL + jl] + tr[LSTART*LL + jl];
    const float m2 = RL(init, 0) * LOG2E;
    float P = act ? exp2f(init * LOG2E - m2) : 0.f;
    float macc = m2;

    STAGE(1,1); STAGE(2,2); STAGE(3,3); STAGE(4,4); STAGE(5,5); STAGE(6,0);
    WAITVM(15);                           // row 1 landed
    float rawA[12], rawB[12];
    {
      const float* rp = ring + 1*ROWF + jl;
      float e1[12];
      #pragma unroll
      for (int k = 0; k < 12; ++k) e1[k] = exp2f(fmaf(rp[(12*w+k)*LL], LOG2E, trg2[k]));
      PARTIALS_L(e1, 1);                  // partials of t=1
    }
    WAITVM(12);                           // row 2 landed
    {
      const float* rp = ring + 2*ROWF + jl;
      #pragma unroll
      for (int k = 0; k < 12; ++k) rawA[k] = rp[(12*w+k)*LL];
    }
    BARRIER();

    int sr = 3, sw = 1;
    #pragma unroll 1
    for (int t = 2; t <= 254; t += 2) {
      ITER_L(t,     rawA, rawB);
      ITER_L(t + 1, rawB, rawA);
    }
    // final merge: step 255
    {
      float Pn = (partS[1][0][j] + partS[1][1][j])
               + (partS[1][2][j] + partS[1][3][j]);
      int rb = __builtin_amdgcn_readlane(__float_as_int(Pn), 0);
      int e  = ((rb >> 23) & 255) - 127;
      const bool upd = (255 < len);
      P    = upd ? __builtin_ldexpf(Pn, -e) : P;
      macc = upd ? macc + (float)e : macc;
    }
    if (tid == LEND) ws[b] = (macc + __log2f(P)) * LN2;   // upto[END] in nats
  }
}

__global__ void viterbi_score(const float* __restrict__ ws, float* __restrict__ out)
{
  int b = threadIdx.x;
  if (b < BB) out[(size_t)BB*TT + b] = ws[BB + b] - ws[b];  // best - upto
}

extern "C" void kernel_launch(void* const* d_in, const int* in_sizes, int n_in,
                              void* d_out, int out_size, void* d_ws, size_t ws_size,
                              hipStream_t stream) {
  const float* em  = (const float*)d_in[0];
  const float* tr  = (const float*)d_in[1];
  const int*   ln  = (const int*)d_in[2];
  float* out = (float*)d_out;
  float* ws  = (float*)d_ws;
  viterbi_fwd<<<dim3(64), dim3(256), 0, stream>>>(em, tr, ln, out, ws);
  viterbi_score<<<dim3(1), dim3(64), 0, stream>>>(ws, out);
}

// Round 11
// 125.662 us; speedup vs baseline: 3.5357x; 1.4705x over previous
//
#include <hip/hip_runtime.h>

// Viterbi decoder forward: B=32, T=256, L=48, START=46, END=47.
// R11 = R3's winning structure (64 WGs: 32 Viterbi + 32 LSE; 4 waves,
// 12 i's/wave, lane j = label; LDS partial merge; raw lgkm-only barrier)
// + pinned register prefetch: plain global loads issued 3 rows ahead,
// forced to materialize 2 rows ahead by an empty "+v" asm (compiler
// emits the counted vmcnt wait at the pin, off the critical chain).
// Merge reads are issued first in each iteration so their LDS latency
// overlaps the load-issue/pin/etr work. LSE in probability domain
// (P = E^T P, ldexp renorm; validated R5/R10).

#define TT 256
#define LL 48
#define ROWF 2304          // 48*48 floats per time-row
#define LSTART 46
#define LEND 47
#define BB 32
#define LOG2E 1.44269504088896f
#define LN2 0.693147180559945f

#define RL(var, lane) __int_as_float(__builtin_amdgcn_readlane(__float_as_int(var), (lane)))

#define BARRIER() do { \
    asm volatile("s_waitcnt lgkmcnt(0)" ::: "memory"); \
    __builtin_amdgcn_s_barrier(); \
  } while (0)

// keep-alive pin: forces the 12 loaded values into live VGPRs HERE; the
// compiler inserts its own (counted) vmcnt wait before this point. No
// constraint races: loads remain compiler-visible ordinary loads.
#define PIN12(B) asm volatile("" : \
    "+v"((B)[0]), "+v"((B)[1]), "+v"((B)[2]),  "+v"((B)[3]), \
    "+v"((B)[4]), "+v"((B)[5]), "+v"((B)[6]),  "+v"((B)[7]), \
    "+v"((B)[8]), "+v"((B)[9]), "+v"((B)[10]), "+v"((B)[11]))

// plain (compiler-managed) load of this lane's 12-element slice of ROW
#define LOADROW(B, ROW) do { \
    const float* q_ = emB + (size_t)(ROW)*ROWF + (size_t)(12*w)*LL + jl; \
    _Pragma("unroll") \
    for (int k = 0; k < 12; ++k) (B)[k] = q_[k*LL]; \
  } while (0)

// strict > with ordered pairing == jnp.argmax first-occurrence semantics
#define AMAX(vx, ix, vy, iy) do { if ((vy) > (vx)) { (vx)=(vy); (ix)=(iy);} } while(0)

// 12-candidate partial max/argmax tree -> partV[PW][w][j]
#define PARTIALS_V(ETR, PW) do { \
    float cv[12]; int ci[12]; \
    _Pragma("unroll") \
    for (int k = 0; k < 12; ++k) { \
      cv[k] = (ETR)[k] + RL(vbest, 12*w + k); ci[k] = 12*w + k; } \
    AMAX(cv[0],ci[0],cv[1],ci[1]);  AMAX(cv[2],ci[2],cv[3],ci[3]); \
    AMAX(cv[4],ci[4],cv[5],ci[5]);  AMAX(cv[6],ci[6],cv[7],ci[7]); \
    AMAX(cv[8],ci[8],cv[9],ci[9]);  AMAX(cv[10],ci[10],cv[11],ci[11]); \
    AMAX(cv[0],ci[0],cv[2],ci[2]);  AMAX(cv[4],ci[4],cv[6],ci[6]); \
    AMAX(cv[8],ci[8],cv[10],ci[10]); \
    AMAX(cv[0],ci[0],cv[4],ci[4]); \
    AMAX(cv[0],ci[0],cv[8],ci[8]); \
    partV[PW][w][j] = make_float2(cv[0], __int_as_float(ci[0])); \
  } while (0)

// Viterbi iteration t: merge step t-1, issue row t+3, pin row t+1 (build
// ETRN off-chain), chain-update vbest, partials of step t, barrier.
#define ITER_V(T_, BISS, BPIN, ETRC, ETRN) do { \
    const int pr_ = ((T_)-1) & 1; \
    float2 m0_ = partV[pr_][0][j], m1_ = partV[pr_][1][j]; \
    float2 m2_ = partV[pr_][2][j], m3_ = partV[pr_][3][j]; \
    { int row_ = (T_) + 3; if (row_ > 255) row_ = 255; LOADROW(BISS, row_); } \
    PIN12(BPIN); \
    _Pragma("unroll") \
    for (int k = 0; k < 12; ++k) (ETRN)[k] = (BPIN)[k] + trg[k]; \
    float bv_ = m0_.x; int ba_ = __float_as_int(m0_.y); \
    AMAX(bv_, ba_, m1_.x, __float_as_int(m1_.y)); \
    AMAX(bv_, ba_, m2_.x, __float_as_int(m2_.y)); \
    AMAX(bv_, ba_, m3_.x, __float_as_int(m3_.y)); \
    { const bool upd_ = act && (((T_)-1) < len); \
      vbest = upd_ ? bv_ : vbest; \
      if (w == 0 && upd_) bp[((T_)-1)*LL + j] = (unsigned char)ba_; } \
    PARTIALS_V(ETRC, (T_) & 1); \
    BARRIER(); \
  } while (0)

#define PARTIALS_L(EE, PW) do { \
    float a0 = 0.f, a1 = 0.f, a2 = 0.f, a3 = 0.f; \
    _Pragma("unroll") \
    for (int k = 0; k < 12; k += 4) { \
      a0 = fmaf((EE)[k+0], RL(P, 12*w + k + 0), a0); \
      a1 = fmaf((EE)[k+1], RL(P, 12*w + k + 1), a1); \
      a2 = fmaf((EE)[k+2], RL(P, 12*w + k + 2), a2); \
      a3 = fmaf((EE)[k+3], RL(P, 12*w + k + 3), a3); \
    } \
    partS[PW][w][j] = (a0 + a1) + (a2 + a3); \
  } while (0)

#define ITER_L(T_, BISS, BPIN, EEC, EEN) do { \
    const int pr_ = ((T_)-1) & 1; \
    float s0_ = partS[pr_][0][j], s1_ = partS[pr_][1][j]; \
    float s2_ = partS[pr_][2][j], s3_ = partS[pr_][3][j]; \
    { int row_ = (T_) + 3; if (row_ > 255) row_ = 255; LOADROW(BISS, row_); } \
    PIN12(BPIN); \
    _Pragma("unroll") \
    for (int k = 0; k < 12; ++k) \
      (EEN)[k] = exp2f(fmaf((BPIN)[k], LOG2E, trg2[k])); \
    float Pn_ = (s0_ + s1_) + (s2_ + s3_); \
    { int rb_ = __builtin_amdgcn_readlane(__float_as_int(Pn_), 0); \
      int e_ = ((rb_ >> 23) & 255) - 127; \
      const bool upd_ = (((T_)-1) < len); \
      P    = upd_ ? __builtin_ldexpf(Pn_, -e_) : P; \
      macc = upd_ ? macc + (float)e_ : macc; } \
    PARTIALS_L(EEC, (T_) & 1); \
    BARRIER(); \
  } while (0)

__device__ __forceinline__ int load_len(const int* len_raw, int b) {
  // lengths int32-or-int64 detection (values 128..256)
  bool is64 = (len_raw[1] == 0) && (len_raw[3] == 0) && (len_raw[5] == 0);
  int len = is64 ? len_raw[2*b] : len_raw[b];
  if (len > TT) len = TT;
  if (len < 1) len = 1;
  return len;
}

__launch_bounds__(256, 1)
__global__ void viterbi_fwd(const float* __restrict__ em,
                            const float* __restrict__ tr,
                            const int* __restrict__ len_raw,
                            float* __restrict__ out,
                            float* __restrict__ ws)
{
  const int role = blockIdx.x >> 5;   // 0 = Viterbi, 1 = LSE
  const int b    = blockIdx.x & 31;
  const int tid  = threadIdx.x;
  const int w    = tid >> 6;
  const int j    = tid & 63;
  const bool act = (j < LL);
  const int jl   = act ? j : (LL - 1);
  const int len  = load_len(len_raw, b);

  __shared__ float2 partV[2][4][64];
  __shared__ float  partS[2][4][64];
  __shared__ unsigned char bp[TT*LL];
  __shared__ unsigned char cmp_[16*LL];
  __shared__ unsigned char entry_[16];
  __shared__ unsigned char raw[TT];

  const float* emB = em + (size_t)b*TT*ROWF;

  if (role == 0) {
    // ===================== Viterbi =====================
    for (int idx = tid; idx < LL; idx += 256) bp[idx] = (unsigned char)LSTART;
    for (int idx = len*LL + tid; idx < TT*LL; idx += 256) bp[idx] = (unsigned char)LEND;
    __syncthreads();

    float trg[12];
    #pragma unroll
    for (int k = 0; k < 12; ++k) trg[k] = tr[(12*w + k)*LL + jl];
    const float init = emB[LSTART*LL + jl] + tr[LSTART*LL + jl];
    float vbest = act ? init : -INFINITY;

    float B0[12], B1[12], B2[12], B3[12], etrA[12], etrB[12];
    // prologue: rows 1..3; partials of step 1; row 4; etrA = row 2
    LOADROW(B1, 1); LOADROW(B2, 2); LOADROW(B3, 3);
    PIN12(B1);
    {
      float e1[12];
      #pragma unroll
      for (int k = 0; k < 12; ++k) e1[k] = B1[k] + trg[k];
      PARTIALS_V(e1, 1);
    }
    LOADROW(B0, 4);
    PIN12(B2);
    #pragma unroll
    for (int k = 0; k < 12; ++k) etrA[k] = B2[k] + trg[k];
    BARRIER();

    // loop t = 2..253 (63 quad blocks), then peel 254, 255
    #pragma unroll 1
    for (int m = 0; m < 63; ++m) {
      const int t0 = 4*m + 2;
      ITER_V(t0,     B1, B3, etrA, etrB);
      ITER_V(t0 + 1, B2, B0, etrB, etrA);
      ITER_V(t0 + 2, B3, B1, etrA, etrB);
      ITER_V(t0 + 3, B0, B2, etrB, etrA);
    }
    // t=254: no new issue needed; pin row 255 (in B3)
    {
      const int pr_ = 253 & 1;
      float2 m0_ = partV[pr_][0][j], m1_ = partV[pr_][1][j];
      float2 m2_ = partV[pr_][2][j], m3_ = partV[pr_][3][j];
      PIN12(B3);
      #pragma unroll
      for (int k = 0; k < 12; ++k) etrB[k] = B3[k] + trg[k];
      float bv_ = m0_.x; int ba_ = __float_as_int(m0_.y);
      AMAX(bv_, ba_, m1_.x, __float_as_int(m1_.y));
      AMAX(bv_, ba_, m2_.x, __float_as_int(m2_.y));
      AMAX(bv_, ba_, m3_.x, __float_as_int(m3_.y));
      const bool upd_ = act && (253 < len);
      vbest = upd_ ? bv_ : vbest;
      if (w == 0 && upd_) bp[253*LL + j] = (unsigned char)ba_;
      PARTIALS_V(etrA, 0);
      BARRIER();
    }
    // t=255
    {
      float2 m0_ = partV[0][0][j], m1_ = partV[0][1][j];
      float2 m2_ = partV[0][2][j], m3_ = partV[0][3][j];
      float bv_ = m0_.x; int ba_ = __float_as_int(m0_.y);
      AMAX(bv_, ba_, m1_.x, __float_as_int(m1_.y));
      AMAX(bv_, ba_, m2_.x, __float_as_int(m2_.y));
      AMAX(bv_, ba_, m3_.x, __float_as_int(m3_.y));
      const bool upd_ = act && (254 < len);
      vbest = upd_ ? bv_ : vbest;
      if (w == 0 && upd_) bp[254*LL + j] = (unsigned char)ba_;
      PARTIALS_V(etrB, 1);
      BARRIER();
    }
    // final merge: step 255 partials in partV[1]
    {
      float2 m0 = partV[1][0][j], m1 = partV[1][1][j];
      float2 m2 = partV[1][2][j], m3 = partV[1][3][j];
      float bv = m0.x; int ba = __float_as_int(m0.y);
      AMAX(bv, ba, m1.x, __float_as_int(m1.y));
      AMAX(bv, ba, m2.x, __float_as_int(m2.y));
      AMAX(bv, ba, m3.x, __float_as_int(m3.y));
      const bool upd = act && (255 < len);
      vbest = upd ? bv : vbest;
      if (w == 0 && upd) bp[255*LL + j] = (unsigned char)ba;
    }
    if (tid == LEND) ws[BB + b] = vbest;  // best[END]
    __syncthreads();

    // ---- traceback, chunked (16 chunks x 16 steps) ----
    for (int idx = tid; idx < 16*LL; idx += 256) {
      int c = idx / LL, l = idx - c*LL;
      int pc = l;
      #pragma unroll
      for (int k = 15; k >= 0; --k) pc = bp[(16*c + k)*LL + pc];
      cmp_[c*LL + l] = (unsigned char)pc;
    }
    __syncthreads();
    if (tid == 0) {
      int pc = LEND;
      for (int c = 15; c >= 0; --c) { entry_[c] = (unsigned char)pc; pc = cmp_[c*LL + pc]; }
    }
    __syncthreads();
    if (tid < 16) {
      int c = tid, pc = entry_[c];
      #pragma unroll
      for (int k = 15; k >= 0; --k) { int t2 = 16*c + k; pc = bp[t2*LL + pc]; raw[t2] = (unsigned char)pc; }
    }
    __syncthreads();
    out[(size_t)b*TT + tid] = (tid < TT - 1) ? (float)raw[tid + 1] : (float)LEND;

  } else {
    // ===================== logsumexp (probability domain) =====================
    float trg2[12];
    #pragma unroll
    for (int k = 0; k < 12; ++k) trg2[k] = tr[(12*w + k)*LL + jl] * LOG2E;
    const float init = emB[LSTART*LL + jl] + tr[LSTART*LL + jl];
    const float m2 = RL(init, 0) * LOG2E;
    float P = act ? exp2f(init * LOG2E - m2) : 0.f;
    float macc = m2;

    float B0[12], B1[12], B2[12], B3[12], eeA[12], eeB[12];
    LOADROW(B1, 1); LOADROW(B2, 2); LOADROW(B3, 3);
    PIN12(B1);
    {
      float e1[12];
      #pragma unroll
      for (int k = 0; k < 12; ++k) e1[k] = exp2f(fmaf(B1[k], LOG2E, trg2[k]));
      PARTIALS_L(e1, 1);
    }
    LOADROW(B0, 4);
    PIN12(B2);
    #pragma unroll
    for (int k = 0; k < 12; ++k) eeA[k] = exp2f(fmaf(B2[k], LOG2E, trg2[k]));
    BARRIER();

    #pragma unroll 1
    for (int m = 0; m < 63; ++m) {
      const int t0 = 4*m + 2;
      ITER_L(t0,     B1, B3, eeA, eeB);
      ITER_L(t0 + 1, B2, B0, eeB, eeA);
      ITER_L(t0 + 2, B3, B1, eeA, eeB);
      ITER_L(t0 + 3, B0, B2, eeB, eeA);
    }
    // t=254
    {
      const int pr_ = 253 & 1;
      float s0_ = partS[pr_][0][j], s1_ = partS[pr_][1][j];
      float s2_ = partS[pr_][2][j], s3_ = partS[pr_][3][j];
      PIN12(B3);
      #pragma unroll
      for (int k = 0; k < 12; ++k) eeB[k] = exp2f(fmaf(B3[k], LOG2E, trg2[k]));
      float Pn_ = (s0_ + s1_) + (s2_ + s3_);
      int rb_ = __builtin_amdgcn_readlane(__float_as_int(Pn_), 0);
      int e_ = ((rb_ >> 23) & 255) - 127;
      const bool upd_ = (253 < len);
      P    = upd_ ? __builtin_ldexpf(Pn_, -e_) : P;
      macc = upd_ ? macc + (float)e_ : macc;
      PARTIALS_L(eeA, 0);
      BARRIER();
    }
    // t=255
    {
      float s0_ = partS[0][0][j], s1_ = partS[0][1][j];
      float s2_ = partS[0][2][j], s3_ = partS[0][3][j];
      float Pn_ = (s0_ + s1_) + (s2_ + s3_);
      int rb_ = __builtin_amdgcn_readlane(__float_as_int(Pn_), 0);
      int e_ = ((rb_ >> 23) & 255) - 127;
      const bool upd_ = (254 < len);
      P    = upd_ ? __builtin_ldexpf(Pn_, -e_) : P;
      macc = upd_ ? macc + (float)e_ : macc;
      PARTIALS_L(eeB, 1);
      BARRIER();
    }
    // final merge: step 255
    {
      float Pn = (partS[1][0][j] + partS[1][1][j])
               + (partS[1][2][j] + partS[1][3][j]);
      int rb = __builtin_amdgcn_readlane(__float_as_int(Pn), 0);
      int e  = ((rb >> 23) & 255) - 127;
      const bool upd = (255 < len);
      P    = upd ? __builtin_ldexpf(Pn, -e) : P;
      macc = upd ? macc + (float)e : macc;
    }
    if (tid == LEND) ws[b] = (macc + __log2f(P)) * LN2;   // upto[END] in nats
  }
}

__global__ void viterbi_score(const float* __restrict__ ws, float* __restrict__ out)
{
  int b = threadIdx.x;
  if (b < BB) out[(size_t)BB*TT + b] = ws[BB + b] - ws[b];  // best - upto
}

extern "C" void kernel_launch(void* const* d_in, const int* in_sizes, int n_in,
                              void* d_out, int out_size, void* d_ws, size_t ws_size,
                              hipStream_t stream) {
  const float* em  = (const float*)d_in[0];
  const float* tr  = (const float*)d_in[1];
  const int*   ln  = (const int*)d_in[2];
  float* out = (float*)d_out;
  float* ws  = (float*)d_ws;
  viterbi_fwd<<<dim3(64), dim3(256), 0, stream>>>(em, tr, ln, out, ws);
  viterbi_score<<<dim3(1), dim3(64), 0, stream>>>(ws, out);
}